// Round 2
// baseline (2735.689 us; speedup 1.0000x reference)
//
#include <hip/hip_runtime.h>
#include <cstddef>

#define NN 12288
#define FF 512

using half8 = __attribute__((ext_vector_type(8))) _Float16;
using half4 = __attribute__((ext_vector_type(4))) _Float16;
using half2v = __attribute__((ext_vector_type(2))) _Float16;
using f32x4 = __attribute__((ext_vector_type(4))) float;

constexpr int BM = 32;             // query rows per block
constexpr int BN = 32;             // keys per tile
constexpr int KA_S = 520;          // kA row stride (f16): 1040B -> 4-bank step, 2-way max
constexpr int KT_S = 40;           // kT row stride (f16): 80B -> b128-aligned, 2-way max
constexpr int PB_S = 40;           // pbuf row stride (f16)
constexpr float MASK_NEG = -1e9f;  // Keras additive mask constant

// ---------------- prepass 1: features fp32 -> fp16 (row-major) ----------------
__global__ void cvt_feat_kernel(const float* __restrict__ in, _Float16* __restrict__ out) {
    const size_t i = ((size_t)blockIdx.x * blockDim.x + threadIdx.x) * 8;
    float4 x = *reinterpret_cast<const float4*>(in + i);
    float4 y = *reinterpret_cast<const float4*>(in + i + 4);
    half8 h;
    h[0] = (_Float16)x.x; h[1] = (_Float16)x.y; h[2] = (_Float16)x.z; h[3] = (_Float16)x.w;
    h[4] = (_Float16)y.x; h[5] = (_Float16)y.y; h[6] = (_Float16)y.z; h[7] = (_Float16)y.w;
    *reinterpret_cast<half8*>(out + i) = h;
}

// ---------------- prepass 2: featT[f][n] = (fp16) features[n][f] ----------------
__global__ void transpose_feat_kernel(const float* __restrict__ in, _Float16* __restrict__ outT) {
    __shared__ float tile[32][33];
    const int bi = blockIdx.x;              // n-tile (384)
    const int bj = blockIdx.y;              // f-tile (16)
    const int r  = threadIdx.x >> 3;        // 0..31
    const int c4 = (threadIdx.x & 7) << 2;  // 0,4..28
    float4 v = *reinterpret_cast<const float4*>(in + (size_t)(bi * 32 + r) * FF + bj * 32 + c4);
    tile[r][c4 + 0] = v.x; tile[r][c4 + 1] = v.y; tile[r][c4 + 2] = v.z; tile[r][c4 + 3] = v.w;
    __syncthreads();
    half4 h;
#pragma unroll
    for (int k = 0; k < 4; ++k) h[k] = (_Float16)tile[c4 + k][r];
    *reinterpret_cast<half4*>(outT + (size_t)(bj * 32 + r) * NN + bi * 32 + c4) = h;
}

// ---------------- fused masked attention, flash-style ----------------
// 256 threads = 4 waves, BM=32 rows, BN=32 keys/tile, grid 384 (2 blocks/CU).
// QK role: wave (rg=wid>>1, ch=wid&1) computes S[16rg..+16][16ch..+16], K=512 -> 16 MFMAs.
// PV role: wave owns feat cols [128*wid, 128*wid+128): rf(2) x cf(8), K=32 -> 16 MFMAs.
// MFMA 16x16x32 f16; C: col=lane&15, row=4*(lane>>4)+reg. A row / B col = lane&15,
// k = (lane>>4)*8+j for both (k-grouping identical -> natural key order everywhere).
// MODE: 2 = feath+featT in ws, 1 = featT only (fp32 K/Q loads), 0 = no ws (slow stage).
template<int MODE>
__global__ __launch_bounds__(256, 2)
void attn_main(const float* __restrict__ featf, const _Float16* __restrict__ feath,
               const _Float16* __restrict__ featT, const int* __restrict__ Amat,
               float* __restrict__ out) {
    __shared__ alignas(16) _Float16 kA[BN * KA_S];     // 33280 B  K tile, key-major
    __shared__ alignas(16) _Float16 kT[FF * KT_S];     // 40960 B  V tile, feat-major
    __shared__ alignas(16) _Float16 pbuf[BM * PB_S];   //  2560 B  P (probs)
    __shared__ alignas(16) float pmax_s[BM][2];
    __shared__ alignas(16) float psum_s[BM][2];
    __shared__ alignas(16) float m_s[BM];
    __shared__ alignas(16) float m_new[BM];
    __shared__ alignas(16) float l_s[BM];
    __shared__ alignas(16) float rscale_s[BM];

    const int tid  = threadIdx.x;
    const int lane = tid & 63;
    const int wid  = tid >> 6;      // 0..3
    const int g    = lane >> 4;     // 0..3
    const int a    = lane & 15;     // 0..15
    const int rg   = wid >> 1;      // QK row-group (0..1)
    const int ch   = wid & 1;       // QK key-half (0..1)
    const int qrow0 = blockIdx.x * BM;

    // ---- Q fragments in registers (A-operand: row=lane&15, k=(lane>>4)*8+j) ----
    half8 qf[16];
    {
        const int qr = qrow0 + 16 * rg + a;
#pragma unroll
        for (int ks = 0; ks < 16; ++ks) {
            const int f0 = 32 * ks + 8 * g;
            if constexpr (MODE == 2) {
                qf[ks] = *reinterpret_cast<const half8*>(feath + (size_t)qr * FF + f0);
            } else {
                const float* sp = featf + (size_t)qr * FF + f0;
                float4 x = *reinterpret_cast<const float4*>(sp);
                float4 y = *reinterpret_cast<const float4*>(sp + 4);
                half8 h;
                h[0] = (_Float16)x.x; h[1] = (_Float16)x.y; h[2] = (_Float16)x.z; h[3] = (_Float16)x.w;
                h[4] = (_Float16)y.x; h[5] = (_Float16)y.y; h[6] = (_Float16)y.z; h[7] = (_Float16)y.w;
                qf[ks] = h;
            }
        }
    }

    f32x4 acc[2][8];
#pragma unroll
    for (int i = 0; i < 2; ++i)
#pragma unroll
        for (int j = 0; j < 8; ++j) acc[i][j] = f32x4{0.f, 0.f, 0.f, 0.f};

    if (tid < BM) { m_s[tid] = -INFINITY; l_s[tid] = 0.f; }
    __syncthreads();

    for (int kt = 0; kt < NN / BN; ++kt) {
        const int key0 = kt * BN;

        // ---- stage kA (key-major): 32 keys x 512 f16, b128 both sides ----
#pragma unroll
        for (int i = 0; i < 8; ++i) {
            const int flat  = tid + 256 * i;   // 0..2047
            const int key   = flat >> 6;       // 0..31
            const int chunk = flat & 63;       // 8-f16 chunk
            _Float16* dst = &kA[key * KA_S + chunk * 8];
            if constexpr (MODE == 2) {
                *reinterpret_cast<half8*>(dst) =
                    *reinterpret_cast<const half8*>(feath + (size_t)(key0 + key) * FF + chunk * 8);
            } else {
                const float* sp = featf + (size_t)(key0 + key) * FF + chunk * 8;
                float4 x = *reinterpret_cast<const float4*>(sp);
                float4 y = *reinterpret_cast<const float4*>(sp + 4);
                half8 h;
                h[0] = (_Float16)x.x; h[1] = (_Float16)x.y; h[2] = (_Float16)x.z; h[3] = (_Float16)x.w;
                h[4] = (_Float16)y.x; h[5] = (_Float16)y.y; h[6] = (_Float16)y.z; h[7] = (_Float16)y.w;
                *reinterpret_cast<half8*>(dst) = h;
            }
        }

        // ---- stage kT (feat-major): 512 feats x 32 keys ----
        if constexpr (MODE >= 1) {
#pragma unroll
            for (int i = 0; i < 8; ++i) {
                const int flat = tid + 256 * i;   // 0..2047
                const int feat = flat >> 2;       // 0..511
                const int part = flat & 3;        // 8-key chunk
                *reinterpret_cast<half8*>(&kT[feat * KT_S + part * 8]) =
                    *reinterpret_cast<const half8*>(featT + (size_t)feat * NN + key0 + part * 8);
            }
        } else {
            // slow correctness path: gather fp32 columns
#pragma unroll 4
            for (int i = 0; i < 32; ++i) {
                const int task = tid + 256 * i;   // 0..8191
                const int feat = task >> 4;       // 0..511
                const int kp   = task & 15;       // key pair
                const float x0 = featf[(size_t)(key0 + 2 * kp) * FF + feat];
                const float x1 = featf[(size_t)(key0 + 2 * kp + 1) * FF + feat];
                half2v h; h[0] = (_Float16)x0; h[1] = (_Float16)x1;
                *reinterpret_cast<half2v*>(&kT[feat * KT_S + 2 * kp]) = h;
            }
        }

        // ---- A-mask prefetch (HBM stream, consumed after QK) ----
        int am[4];
#pragma unroll
        for (int r = 0; r < 4; ++r) {
            const int arow = qrow0 + 16 * rg + 4 * g + r;
            const int acol = key0 + 16 * ch + a;
            am[r] = Amat[(size_t)arow * NN + acol];
        }
        __syncthreads();   // B2: tiles staged

        // ---- QK^T: 1 fragment per wave, K=512 ----
        f32x4 s{0.f, 0.f, 0.f, 0.f};
        const _Float16* kr = &kA[(16 * ch + a) * KA_S];
#pragma unroll
        for (int ks = 0; ks < 16; ++ks) {
            const half8 bf = *reinterpret_cast<const half8*>(kr + 32 * ks + 8 * g);
            s = __builtin_amdgcn_mfma_f32_16x16x32_f16(qf[ks], bf, s, 0, 0, 0);
        }

        // ---- mask + per-row tile max (16 key-lanes reduce, halves via LDS) ----
        float sv[4];
#pragma unroll
        for (int r = 0; r < 4; ++r) sv[r] = (am[r] > 0) ? s[r] : MASK_NEG;
#pragma unroll
        for (int r = 0; r < 4; ++r) {
            float v = sv[r];
            v = fmaxf(v, __shfl_xor(v, 1, 16));
            v = fmaxf(v, __shfl_xor(v, 2, 16));
            v = fmaxf(v, __shfl_xor(v, 4, 16));
            v = fmaxf(v, __shfl_xor(v, 8, 16));
            if (a == 0) pmax_s[16 * rg + 4 * g + r][ch] = v;
        }
        __syncthreads();   // B3: pmax visible

        // ---- P = exp(s - m_new); fp16 P; partial sums; stats (single-writer) ----
#pragma unroll
        for (int r = 0; r < 4; ++r) {
            const int row = 16 * rg + 4 * g + r;
            const float mo = m_s[row];
            const float mn = fmaxf(mo, fmaxf(pmax_s[row][0], pmax_s[row][1]));
            const float p  = __expf(sv[r] - mn);
            pbuf[row * PB_S + 16 * ch + a] = (_Float16)p;
            float ss = p;
            ss += __shfl_xor(ss, 1, 16);
            ss += __shfl_xor(ss, 2, 16);
            ss += __shfl_xor(ss, 4, 16);
            ss += __shfl_xor(ss, 8, 16);
            if (a == 0) {
                psum_s[row][ch] = ss;
                if (ch == 0) { m_new[row] = mn; rscale_s[row] = __expf(mo - mn); }
            }
        }
        __syncthreads();   // B4: P, psum, rscale visible

        // ---- rescale O; l/m update; PV ----
#pragma unroll
        for (int rf = 0; rf < 2; ++rf) {
            const float4 scv = *reinterpret_cast<const float4*>(&rscale_s[16 * rf + 4 * g]);
#pragma unroll
            for (int cf = 0; cf < 8; ++cf) {
                acc[rf][cf][0] *= scv.x; acc[rf][cf][1] *= scv.y;
                acc[rf][cf][2] *= scv.z; acc[rf][cf][3] *= scv.w;
            }
        }
        if (tid < BM) {
            l_s[tid] = l_s[tid] * rscale_s[tid] + psum_s[tid][0] + psum_s[tid][1];
            m_s[tid] = m_new[tid];
        }
        half8 pa[2];
#pragma unroll
        for (int rf = 0; rf < 2; ++rf)
            pa[rf] = *reinterpret_cast<const half8*>(&pbuf[(16 * rf + a) * PB_S + 8 * g]);
#pragma unroll
        for (int cf = 0; cf < 8; ++cf) {
            const int feat = (wid << 7) + (cf << 4) + a;
            const half8 vb = *reinterpret_cast<const half8*>(&kT[feat * KT_S + 8 * g]);
#pragma unroll
            for (int rf = 0; rf < 2; ++rf)
                acc[rf][cf] = __builtin_amdgcn_mfma_f32_16x16x32_f16(pa[rf], vb, acc[rf][cf], 0, 0, 0);
        }
        __syncthreads();   // Bend: PV done, buffers reusable
    }

    // ---- epilogue: O / l ----
#pragma unroll
    for (int rf = 0; rf < 2; ++rf) {
        const float4 lv = *reinterpret_cast<const float4*>(&l_s[16 * rf + 4 * g]);
        const float inv[4] = {1.f / lv.x, 1.f / lv.y, 1.f / lv.z, 1.f / lv.w};
#pragma unroll
        for (int cf = 0; cf < 8; ++cf) {
            const int col = (wid << 7) + (cf << 4) + a;
#pragma unroll
            for (int r = 0; r < 4; ++r) {
                out[(size_t)(qrow0 + 16 * rf + 4 * g + r) * FF + col] = acc[rf][cf][r] * inv[r];
            }
        }
    }
}

extern "C" void kernel_launch(void* const* d_in, const int* in_sizes, int n_in,
                              void* d_out, int out_size, void* d_ws, size_t ws_size,
                              hipStream_t stream) {
    const float* features = (const float*)d_in[0];
    const int*   Amat     = (const int*)d_in[1];
    float*       out      = (float*)d_out;

    const size_t half_elems = (size_t)NN * FF;              // 6.29M
    const size_t half_bytes = half_elems * sizeof(_Float16); // 12.58 MB
    const int grid = NN / BM;  // 384 blocks

    if (ws_size >= 2 * half_bytes) {
        _Float16* featT = (_Float16*)d_ws;
        _Float16* feath = (_Float16*)d_ws + half_elems;
        transpose_feat_kernel<<<dim3(NN / 32, FF / 32), 256, 0, stream>>>(features, featT);
        cvt_feat_kernel<<<(NN * FF) / (256 * 8), 256, 0, stream>>>(features, feath);
        attn_main<2><<<grid, 256, 0, stream>>>(features, feath, featT, Amat, out);
    } else if (ws_size >= half_bytes) {
        _Float16* featT = (_Float16*)d_ws;
        transpose_feat_kernel<<<dim3(NN / 32, FF / 32), 256, 0, stream>>>(features, featT);
        attn_main<1><<<grid, 256, 0, stream>>>(features, nullptr, featT, Amat, out);
    } else {
        attn_main<0><<<grid, 256, 0, stream>>>(features, nullptr, nullptr, Amat, out);
    }
}

// Round 3
// 772.136 us; speedup vs baseline: 3.5430x; 3.5430x over previous
//
#include <hip/hip_runtime.h>
#include <cstddef>
#include <cstdint>

#define NN 12288
#define FF 512

using half8 = __attribute__((ext_vector_type(8))) _Float16;
using half4 = __attribute__((ext_vector_type(4))) _Float16;
using f32x4 = __attribute__((ext_vector_type(4))) float;

constexpr float MASK_NEG = -1e9f;  // Keras additive mask constant

// ---- async global->LDS 16B helper (wave-uniform LDS base + lane*16 dest) ----
__device__ __forceinline__ void gll16(const void* g, void* l) {
    __builtin_amdgcn_global_load_lds((const __attribute__((address_space(1))) void*)g,
                                     (__attribute__((address_space(3))) void*)l, 16, 0, 0);
}

// ---------------- prepass 1: features fp32 -> fp16 (row-major) ----------------
__global__ void cvt_feat_kernel(const float* __restrict__ in, _Float16* __restrict__ out) {
    const size_t i = ((size_t)blockIdx.x * blockDim.x + threadIdx.x) * 8;
    float4 x = *reinterpret_cast<const float4*>(in + i);
    float4 y = *reinterpret_cast<const float4*>(in + i + 4);
    half8 h;
    h[0] = (_Float16)x.x; h[1] = (_Float16)x.y; h[2] = (_Float16)x.z; h[3] = (_Float16)x.w;
    h[4] = (_Float16)y.x; h[5] = (_Float16)y.y; h[6] = (_Float16)y.z; h[7] = (_Float16)y.w;
    *reinterpret_cast<half8*>(out + i) = h;
}

// ---------------- prepass 2: featT[f][n] = (fp16) features[n][f] ----------------
__global__ void transpose_feat_kernel(const float* __restrict__ in, _Float16* __restrict__ outT) {
    __shared__ float tile[32][33];
    const int bi = blockIdx.x;              // n-tile (384)
    const int bj = blockIdx.y;              // f-tile (16)
    const int r  = threadIdx.x >> 3;        // 0..31
    const int c4 = (threadIdx.x & 7) << 2;  // 0,4..28
    float4 v = *reinterpret_cast<const float4*>(in + (size_t)(bi * 32 + r) * FF + bj * 32 + c4);
    tile[r][c4 + 0] = v.x; tile[r][c4 + 1] = v.y; tile[r][c4 + 2] = v.z; tile[r][c4 + 3] = v.w;
    __syncthreads();
    half4 h;
#pragma unroll
    for (int k = 0; k < 4; ++k) h[k] = (_Float16)tile[c4 + k][r];
    *reinterpret_cast<half4*>(outT + (size_t)(bj * 32 + r) * NN + bi * 32 + c4) = h;
}

// ---------------- GEMM1: S=F*F^T tile, mask, per-tile rowmax, P'=exp(s-m_t) ----------------
// 256 thr = 4 waves, tile 128x128, wave-tile 64x64 (wr=wid>>1, wc=wid&1), BK=32, 16 K-steps.
// MFMA 16x16x32 f16: C col=lane&15, row=4*(lane>>4)+reg; A row=lane&15; B col=lane&15;
// k=(lane>>4)*8+j for A and B.
__global__ __launch_bounds__(256)
void gemm1_exp(const _Float16* __restrict__ feath, const int* __restrict__ Amat,
               _Float16* __restrict__ Pmat, float* __restrict__ m_t) {
    __shared__ alignas(16) _Float16 As[2][128 * 32];
    __shared__ alignas(16) _Float16 Bs[2][128 * 32];
    __shared__ alignas(16) float rowmax2[128][2];

    const int tid = threadIdx.x, lane = tid & 63, wid = tid >> 6;
    const int g = lane >> 4, a = lane & 15;
    const int wr = wid >> 1, wc = wid & 1;
    const int row0 = blockIdx.x * 128, col0 = blockIdx.y * 128;

    f32x4 acc[4][4];
#pragma unroll
    for (int i = 0; i < 4; ++i)
#pragma unroll
        for (int j = 0; j < 4; ++j) acc[i][j] = f32x4{0.f, 0.f, 0.f, 0.f};

    const int lr = lane >> 2;          // 0..15 row within chunk
    const int li = (lane & 3) * 8;     // f16 offset within 32-elem row

    auto stage = [&](int buf, int t) {
#pragma unroll
        for (int c = 0; c < 2; ++c) {
            const int ch = wid * 2 + c;  // 0..7
            gll16(feath + (size_t)(row0 + ch * 16 + lr) * FF + t * 32 + li, &As[buf][ch * 512]);
            gll16(feath + (size_t)(col0 + ch * 16 + lr) * FF + t * 32 + li, &Bs[buf][ch * 512]);
        }
    };

    stage(0, 0);
    __syncthreads();
    int buf = 0;
    for (int t = 0; t < 16; ++t) {
        if (t + 1 < 16) stage(buf ^ 1, t + 1);
        half8 af[4], bf[4];
#pragma unroll
        for (int rf = 0; rf < 4; ++rf)
            af[rf] = *reinterpret_cast<const half8*>(&As[buf][(64 * wr + 16 * rf + a) * 32 + 8 * g]);
#pragma unroll
        for (int cf = 0; cf < 4; ++cf)
            bf[cf] = *reinterpret_cast<const half8*>(&Bs[buf][(64 * wc + 16 * cf + a) * 32 + 8 * g]);
#pragma unroll
        for (int rf = 0; rf < 4; ++rf)
#pragma unroll
            for (int cf = 0; cf < 4; ++cf)
                acc[rf][cf] = __builtin_amdgcn_mfma_f32_16x16x32_f16(af[rf], bf[cf], acc[rf][cf], 0, 0, 0);
        __syncthreads();
        buf ^= 1;
    }

    // ---- epilogue: mask (in place), per-row tile max ----
#pragma unroll
    for (int rf = 0; rf < 4; ++rf) {
#pragma unroll
        for (int r = 0; r < 4; ++r) {
            const int grow = row0 + 64 * wr + 16 * rf + 4 * g + r;
#pragma unroll
            for (int cf = 0; cf < 4; ++cf) {
                const int gcol = col0 + 64 * wc + 16 * cf + a;
                const int am = Amat[(size_t)grow * NN + gcol];
                acc[rf][cf][r] = (am > 0) ? acc[rf][cf][r] : MASK_NEG;
            }
        }
    }
#pragma unroll
    for (int rf = 0; rf < 4; ++rf) {
#pragma unroll
        for (int r = 0; r < 4; ++r) {
            float v = fmaxf(fmaxf(acc[rf][0][r], acc[rf][1][r]), fmaxf(acc[rf][2][r], acc[rf][3][r]));
            v = fmaxf(v, __shfl_xor(v, 1, 16));
            v = fmaxf(v, __shfl_xor(v, 2, 16));
            v = fmaxf(v, __shfl_xor(v, 4, 16));
            v = fmaxf(v, __shfl_xor(v, 8, 16));
            if (a == 0) rowmax2[64 * wr + 16 * rf + 4 * g + r][wc] = v;
        }
    }
    __syncthreads();
    if (tid < 128)
        m_t[(size_t)blockIdx.y * NN + row0 + tid] = fmaxf(rowmax2[tid][0], rowmax2[tid][1]);
    // ---- P' = exp(s - m_t) fp16 ----
#pragma unroll
    for (int rf = 0; rf < 4; ++rf) {
#pragma unroll
        for (int r = 0; r < 4; ++r) {
            const int lrow = 64 * wr + 16 * rf + 4 * g + r;
            const float mt = fmaxf(rowmax2[lrow][0], rowmax2[lrow][1]);
            const size_t rbase = (size_t)(row0 + lrow) * NN + col0 + 64 * wc + a;
#pragma unroll
            for (int cf = 0; cf < 4; ++cf) {
                const float p = __expf(acc[rf][cf][r] - mt);
                Pmat[rbase + 16 * cf] = (_Float16)p;
            }
        }
    }
}

// ---------------- row_stats: m = max_t m_t; l = sum_t e^{m_t-m} * s_t ----------------
__global__ __launch_bounds__(256)
void row_stats_kernel(const _Float16* __restrict__ Pmat, const float* __restrict__ m_t,
                      float* __restrict__ m_row, float* __restrict__ l_row) {
    const int lane = threadIdx.x & 63;
    const int wid  = threadIdx.x >> 6;
    const int row  = blockIdx.x * 4 + wid;

    float v = -3.0e38f;
    for (int kt = lane; kt < 96; kt += 64) v = fmaxf(v, m_t[(size_t)kt * NN + row]);
    v = fmaxf(v, __shfl_xor(v, 1));
    v = fmaxf(v, __shfl_xor(v, 2));
    v = fmaxf(v, __shfl_xor(v, 4));
    v = fmaxf(v, __shfl_xor(v, 8));
    v = fmaxf(v, __shfl_xor(v, 16));
    v = fmaxf(v, __shfl_xor(v, 32));
    const float m = v;

    float l = 0.f;
    const _Float16* prow = Pmat + (size_t)row * NN;
#pragma unroll 2
    for (int it = 0; it < 24; ++it) {
        half8 p = *reinterpret_cast<const half8*>(prow + it * 512 + lane * 8);
        float s = 0.f;
#pragma unroll
        for (int j = 0; j < 8; ++j) s += (float)p[j];
        s += __shfl_xor(s, 1, 16);
        s += __shfl_xor(s, 2, 16);
        s += __shfl_xor(s, 4, 16);
        s += __shfl_xor(s, 8, 16);
        const int kt = it * 4 + (lane >> 4);
        l += __expf(m_t[(size_t)kt * NN + row] - m) * s;
    }
    l += __shfl_xor(l, 16);
    l += __shfl_xor(l, 32);
    if (lane == 0) { m_row[row] = m; l_row[row] = l; }
}

// ---------------- GEMM2: O = scale(P')*F / l ----------------
// 256 thr = 4 waves, tile 128x64, wave-tile 64x32 (rf 4 x cf 2), BK=32, 384 K-steps.
__global__ __launch_bounds__(256)
void gemm2_scale(const _Float16* __restrict__ Pmat, const _Float16* __restrict__ featT,
                 const float* __restrict__ m_t, const float* __restrict__ m_row,
                 const float* __restrict__ l_row, float* __restrict__ out) {
    __shared__ alignas(16) _Float16 As[2][128 * 32];   // P' tile
    __shared__ alignas(16) _Float16 Bs[2][64 * 32];    // V^T tile (feat-major)

    const int tid = threadIdx.x, lane = tid & 63, wid = tid >> 6;
    const int g = lane >> 4, a = lane & 15;
    const int wr = wid >> 1, wc = wid & 1;
    const int row0 = blockIdx.x * 128, col0 = blockIdx.y * 64;

    f32x4 acc[4][2];
#pragma unroll
    for (int i = 0; i < 4; ++i) { acc[i][0] = f32x4{0.f,0.f,0.f,0.f}; acc[i][1] = f32x4{0.f,0.f,0.f,0.f}; }

    float m_r[4];
#pragma unroll
    for (int rf = 0; rf < 4; ++rf) m_r[rf] = m_row[row0 + 64 * wr + 16 * rf + a];

    const int lr = lane >> 2;
    const int li = (lane & 3) * 8;

    auto stage = [&](int buf, int t) {
#pragma unroll
        for (int c = 0; c < 2; ++c) {
            const int ch = wid * 2 + c;  // 0..7
            gll16(Pmat + (size_t)(row0 + ch * 16 + lr) * NN + t * 32 + li, &As[buf][ch * 512]);
        }
        gll16(featT + (size_t)(col0 + wid * 16 + lr) * NN + t * 32 + li, &Bs[buf][wid * 512]);
    };

    stage(0, 0);
    __syncthreads();
    int buf = 0;
    _Float16 sc[4] = {(_Float16)1.f, (_Float16)1.f, (_Float16)1.f, (_Float16)1.f};
    for (int t = 0; t < 384; ++t) {
        if ((t & 3) == 0) {
            const int kt = t >> 2;
#pragma unroll
            for (int rf = 0; rf < 4; ++rf)
                sc[rf] = (_Float16)__expf(m_t[(size_t)kt * NN + row0 + 64 * wr + 16 * rf + a] - m_r[rf]);
        }
        if (t + 1 < 384) stage(buf ^ 1, t + 1);
        half8 af[4], bf[2];
#pragma unroll
        for (int rf = 0; rf < 4; ++rf) {
            af[rf] = *reinterpret_cast<const half8*>(&As[buf][(64 * wr + 16 * rf + a) * 32 + 8 * g]);
            af[rf] = af[rf] * sc[rf];
        }
#pragma unroll
        for (int cf = 0; cf < 2; ++cf)
            bf[cf] = *reinterpret_cast<const half8*>(&Bs[buf][(32 * wc + 16 * cf + a) * 32 + 8 * g]);
#pragma unroll
        for (int rf = 0; rf < 4; ++rf)
#pragma unroll
            for (int cf = 0; cf < 2; ++cf)
                acc[rf][cf] = __builtin_amdgcn_mfma_f32_16x16x32_f16(af[rf], bf[cf], acc[rf][cf], 0, 0, 0);
        __syncthreads();
        buf ^= 1;
    }

#pragma unroll
    for (int rf = 0; rf < 4; ++rf) {
#pragma unroll
        for (int r = 0; r < 4; ++r) {
            const int grow = row0 + 64 * wr + 16 * rf + 4 * g + r;
            const float il = 1.0f / l_row[grow];
#pragma unroll
            for (int cf = 0; cf < 2; ++cf) {
                const int gcol = col0 + 32 * wc + 16 * cf + a;
                out[(size_t)grow * FF + gcol] = acc[rf][cf][r] * il;
            }
        }
    }
}

// =====================================================================
// Fallback: round-1 fused flash kernel (verified, 1355 us)
// =====================================================================
constexpr int BM_ = 64;
constexpr int BN_ = 64;
constexpr int KV_STRIDE = 520;

template<bool RH>
__global__ __launch_bounds__(512, 2)
void attn_flash(const float* __restrict__ featf, const _Float16* __restrict__ feath,
                const int* __restrict__ Amat, float* __restrict__ out) {
    __shared__ alignas(16) _Float16 kv[BN_ * KV_STRIDE];
    __shared__ alignas(16) _Float16 pbuf[BM_][72];
    __shared__ alignas(16) float pmax[BM_][2];
    __shared__ alignas(16) float psum[BM_][2];
    __shared__ alignas(16) float m_s[BM_];
    __shared__ alignas(16) float l_s[BM_];
    __shared__ alignas(16) float rscale[BM_];

    const int tid  = threadIdx.x;
    const int lane = tid & 63;
    const int wid  = tid >> 6;
    const int g    = lane >> 4;
    const int a    = lane & 15;
    const int rg   = wid >> 1;
    const int ch   = wid & 1;
    const int qrow0 = blockIdx.x * BM_;

    half8 qf[16];
    {
        const int qr = qrow0 + 16 * rg + a;
#pragma unroll
        for (int ks = 0; ks < 16; ++ks) {
            const int f0 = 32 * ks + 8 * g;
            if constexpr (RH) {
                qf[ks] = *reinterpret_cast<const half8*>(feath + (size_t)qr * FF + f0);
            } else {
                const float* sp = featf + (size_t)qr * FF + f0;
                float4 x = *reinterpret_cast<const float4*>(sp);
                float4 y = *reinterpret_cast<const float4*>(sp + 4);
                half8 h;
                h[0] = (_Float16)x.x; h[1] = (_Float16)x.y; h[2] = (_Float16)x.z; h[3] = (_Float16)x.w;
                h[4] = (_Float16)y.x; h[5] = (_Float16)y.y; h[6] = (_Float16)y.z; h[7] = (_Float16)y.w;
                qf[ks] = h;
            }
        }
    }

    f32x4 acc[4][4];
#pragma unroll
    for (int i = 0; i < 4; ++i)
#pragma unroll
        for (int j = 0; j < 4; ++j) acc[i][j] = f32x4{0.f, 0.f, 0.f, 0.f};

    if (tid < BM_) { m_s[tid] = -INFINITY; l_s[tid] = 0.f; }
    __syncthreads();

    for (int kt = 0; kt < NN / BN_; ++kt) {
        const int key0 = kt * BN_;
#pragma unroll
        for (int i = 0; i < 8; ++i) {
            const int flat8 = tid + i * 512;
            const int key   = flat8 >> 6;
            const int b     = flat8 & 63;
            const int slot  = (b + (key >> 3)) & 63;
            _Float16* dst = &kv[key * KV_STRIDE + slot * 8];
            if constexpr (RH) {
                *reinterpret_cast<half8*>(dst) =
                    *reinterpret_cast<const half8*>(feath + (size_t)(key0 + key) * FF + b * 8);
            } else {
                const float* sp = featf + (size_t)(key0 + key) * FF + b * 8;
                float4 x = *reinterpret_cast<const float4*>(sp);
                float4 y = *reinterpret_cast<const float4*>(sp + 4);
                half8 h;
                h[0] = (_Float16)x.x; h[1] = (_Float16)x.y; h[2] = (_Float16)x.z; h[3] = (_Float16)x.w;
                h[4] = (_Float16)y.x; h[5] = (_Float16)y.y; h[6] = (_Float16)y.z; h[7] = (_Float16)y.w;
                *reinterpret_cast<half8*>(dst) = h;
            }
        }

        int am[2][4];
#pragma unroll
        for (int fc = 0; fc < 2; ++fc)
#pragma unroll
            for (int r = 0; r < 4; ++r) {
                const int arow = qrow0 + 16 * rg + 4 * g + r;
                const int acol = key0 + 32 * ch + 16 * fc + a;
                am[fc][r] = Amat[(size_t)arow * NN + acol];
            }
        __syncthreads();

        f32x4 s0{0.f, 0.f, 0.f, 0.f}, s1{0.f, 0.f, 0.f, 0.f};
        const int bk0 = 32 * ch + a;
        const int bk1 = bk0 + 16;
        const int kb0 = bk0 >> 3;
        const int kb1 = bk1 >> 3;
        const _Float16* kr0 = &kv[bk0 * KV_STRIDE];
        const _Float16* kr1 = &kv[bk1 * KV_STRIDE];
#pragma unroll
        for (int ks = 0; ks < 16; ++ks) {
            const int b = 4 * ks + g;
            const half8 bf0 = *reinterpret_cast<const half8*>(kr0 + (((b + kb0) & 63) << 3));
            const half8 bf1 = *reinterpret_cast<const half8*>(kr1 + (((b + kb1) & 63) << 3));
            s0 = __builtin_amdgcn_mfma_f32_16x16x32_f16(qf[ks], bf0, s0, 0, 0, 0);
            s1 = __builtin_amdgcn_mfma_f32_16x16x32_f16(qf[ks], bf1, s1, 0, 0, 0);
        }

        float sv[2][4];
#pragma unroll
        for (int r = 0; r < 4; ++r) {
            sv[0][r] = (am[0][r] > 0) ? s0[r] : MASK_NEG;
            sv[1][r] = (am[1][r] > 0) ? s1[r] : MASK_NEG;
        }
#pragma unroll
        for (int r = 0; r < 4; ++r) {
            float v = fmaxf(sv[0][r], sv[1][r]);
            v = fmaxf(v, __shfl_xor(v, 1, 16));
            v = fmaxf(v, __shfl_xor(v, 2, 16));
            v = fmaxf(v, __shfl_xor(v, 4, 16));
            v = fmaxf(v, __shfl_xor(v, 8, 16));
            if (a == 0) pmax[16 * rg + 4 * g + r][ch] = v;
        }
        __syncthreads();

#pragma unroll
        for (int r = 0; r < 4; ++r) {
            const int row = 16 * rg + 4 * g + r;
            const float mo = m_s[row];
            const float mn = fmaxf(mo, fmaxf(pmax[row][0], pmax[row][1]));
            const float p0 = __expf(sv[0][r] - mn);
            const float p1 = __expf(sv[1][r] - mn);
            pbuf[row][32 * ch + a]      = (_Float16)p0;
            pbuf[row][32 * ch + 16 + a] = (_Float16)p1;
            float ssum = p0 + p1;
            ssum += __shfl_xor(ssum, 1, 16);
            ssum += __shfl_xor(ssum, 2, 16);
            ssum += __shfl_xor(ssum, 4, 16);
            ssum += __shfl_xor(ssum, 8, 16);
            if (a == 0) psum[row][ch] = ssum;
        }
        __syncthreads();

        if (tid < BM_) {
            const float mo = m_s[tid];
            const float mn = fmaxf(mo, fmaxf(pmax[tid][0], pmax[tid][1]));
            const float sc = __expf(mo - mn);
            l_s[tid] = l_s[tid] * sc + psum[tid][0] + psum[tid][1];
            m_s[tid] = mn;
            rscale[tid] = sc;
        }
        __syncthreads();

#pragma unroll
        for (int rf = 0; rf < 4; ++rf) {
            const float4 scv = *reinterpret_cast<const float4*>(&rscale[16 * rf + 4 * g]);
#pragma unroll
            for (int cf = 0; cf < 4; ++cf) {
                acc[rf][cf][0] *= scv.x; acc[rf][cf][1] *= scv.y;
                acc[rf][cf][2] *= scv.z; acc[rf][cf][3] *= scv.w;
            }
        }
#pragma unroll
        for (int kk = 0; kk < 2; ++kk) {
            half8 af[4];
#pragma unroll
            for (int rf = 0; rf < 4; ++rf)
                af[rf] = *reinterpret_cast<const half8*>(&pbuf[16 * rf + a][32 * kk + 8 * g]);
            const int keybase = 32 * kk + 8 * g;
#pragma unroll
            for (int cf = 0; cf < 4; ++cf) {
                const int col  = 64 * wid + 16 * cf + a;
                const int slot = (((col >> 3) + 4 * kk + g) & 63);
                const _Float16* vb = &kv[(size_t)keybase * KV_STRIDE + (slot << 3) + (col & 7)];
                half8 bf;
#pragma unroll
                for (int j = 0; j < 8; ++j)
                    bf[j] = vb[j * KV_STRIDE];
#pragma unroll
                for (int rf = 0; rf < 4; ++rf)
                    acc[rf][cf] = __builtin_amdgcn_mfma_f32_16x16x32_f16(af[rf], bf, acc[rf][cf], 0, 0, 0);
            }
        }
        __syncthreads();
    }

#pragma unroll
    for (int rf = 0; rf < 4; ++rf) {
        const float4 lv = *reinterpret_cast<const float4*>(&l_s[16 * rf + 4 * g]);
        const float inv[4] = {1.f / lv.x, 1.f / lv.y, 1.f / lv.z, 1.f / lv.w};
#pragma unroll
        for (int cf = 0; cf < 4; ++cf) {
            const int col = 64 * wid + 16 * cf + a;
#pragma unroll
            for (int r = 0; r < 4; ++r) {
                out[(size_t)(qrow0 + 16 * rf + 4 * g + r) * FF + col] = acc[rf][cf][r] * inv[r];
            }
        }
    }
}

extern "C" void kernel_launch(void* const* d_in, const int* in_sizes, int n_in,
                              void* d_out, int out_size, void* d_ws, size_t ws_size,
                              hipStream_t stream) {
    const float* features = (const float*)d_in[0];
    const int*   Amat     = (const int*)d_in[1];
    float*       out      = (float*)d_out;

    // workspace layout for the two-pass path
    const size_t P_bytes   = (size_t)NN * NN * 2;        // 301,989,888
    const size_t f16_bytes = (size_t)NN * FF * 2;        // 12,582,912
    const size_t mt_bytes  = (size_t)96 * NN * 4;        // 4,718,592
    const size_t mrow_b    = (size_t)NN * 4;             // 49,152
    const size_t total     = P_bytes + 2 * f16_bytes + mt_bytes + 2 * mrow_b;  // ~332 MB

    if (ws_size >= total) {
        char* w = (char*)d_ws;
        _Float16* Pmat  = (_Float16*)w;                       w += P_bytes;
        _Float16* feath = (_Float16*)w;                       w += f16_bytes;
        _Float16* featT = (_Float16*)w;                       w += f16_bytes;
        float*    m_t   = (float*)w;                          w += mt_bytes;
        float*    m_row = (float*)w;                          w += mrow_b;
        float*    l_row = (float*)w;

        cvt_feat_kernel<<<(NN * FF) / (256 * 8), 256, 0, stream>>>(features, feath);
        transpose_feat_kernel<<<dim3(NN / 32, FF / 32), 256, 0, stream>>>(features, featT);
        gemm1_exp<<<dim3(NN / 128, NN / 128), 256, 0, stream>>>(feath, Amat, Pmat, m_t);
        row_stats_kernel<<<NN / 4, 256, 0, stream>>>(Pmat, m_t, m_row, l_row);
        gemm2_scale<<<dim3(NN / 128, FF / 64), 256, 0, stream>>>(Pmat, featT, m_t, m_row, l_row, out);
    } else if (ws_size >= f16_bytes) {
        _Float16* feath = (_Float16*)d_ws;
        cvt_feat_kernel<<<(NN * FF) / (256 * 8), 256, 0, stream>>>(features, feath);
        attn_flash<true><<<NN / BM_, 512, 0, stream>>>(features, feath, Amat, out);
    } else {
        attn_flash<false><<<NN / BM_, 512, 0, stream>>>(features, nullptr, Amat, out);
    }
}